// Round 2
// baseline (505.953 us; speedup 1.0000x reference)
//
#include <hip/hip_runtime.h>

#define NBLOCKS  2048
#define NTHREADS 256

// Stage 1: grid-stride float4 squared-diff accumulation, one partial per block.
__global__ __launch_bounds__(NTHREADS) void mse_partial_kernel(
    const float4* __restrict__ yhat4, const float4* __restrict__ y4,
    float* __restrict__ partial, long n4) {
  long idx    = (long)blockIdx.x * blockDim.x + threadIdx.x;
  long stride = (long)gridDim.x * blockDim.x;

  float acc = 0.0f;
  for (long i = idx; i < n4; i += stride) {
    float4 a = yhat4[i];
    float4 b = y4[i];
    float d0 = a.x - b.x;
    float d1 = a.y - b.y;
    float d2 = a.z - b.z;
    float d3 = a.w - b.w;
    acc += d0 * d0 + d1 * d1 + d2 * d2 + d3 * d3;
  }

  // wave-64 reduction
  #pragma unroll
  for (int off = 32; off > 0; off >>= 1)
    acc += __shfl_down(acc, off, 64);

  __shared__ float smem[NTHREADS / 64];
  int lane = threadIdx.x & 63;
  int wid  = threadIdx.x >> 6;
  if (lane == 0) smem[wid] = acc;
  __syncthreads();

  if (threadIdx.x == 0) {
    float s = 0.0f;
    #pragma unroll
    for (int i = 0; i < NTHREADS / 64; ++i) s += smem[i];
    partial[blockIdx.x] = s;
  }
}

// Stage 2: one block reduces NBLOCKS partials (double accum), scales by 1/N.
__global__ __launch_bounds__(NTHREADS) void mse_final_kernel(
    const float* __restrict__ partial, float* __restrict__ out,
    int nparts, double inv_n) {
  double acc = 0.0;
  for (int i = threadIdx.x; i < nparts; i += blockDim.x)
    acc += (double)partial[i];

  #pragma unroll
  for (int off = 32; off > 0; off >>= 1)
    acc += __shfl_down(acc, off, 64);

  __shared__ double smem[NTHREADS / 64];
  int lane = threadIdx.x & 63;
  int wid  = threadIdx.x >> 6;
  if (lane == 0) smem[wid] = acc;
  __syncthreads();

  if (threadIdx.x == 0) {
    double s = 0.0;
    #pragma unroll
    for (int i = 0; i < NTHREADS / 64; ++i) s += smem[i];
    out[0] = (float)(s * inv_n);
  }
}

extern "C" void kernel_launch(void* const* d_in, const int* in_sizes, int n_in,
                              void* d_out, int out_size, void* d_ws, size_t ws_size,
                              hipStream_t stream) {
  const float* yhat = (const float*)d_in[0];
  const float* y    = (const float*)d_in[1];
  float* out        = (float*)d_out;
  float* partial    = (float*)d_ws;  // NBLOCKS floats = 8 KiB

  long n  = (long)in_sizes[0];       // 16384 * 4096, divisible by 4
  long n4 = n / 4;

  mse_partial_kernel<<<NBLOCKS, NTHREADS, 0, stream>>>(
      (const float4*)yhat, (const float4*)y, partial, n4);
  mse_final_kernel<<<1, NTHREADS, 0, stream>>>(
      partial, out, (int)NBLOCKS, 1.0 / (double)n);
}